// Round 5
// baseline (13.137 us; speedup 1.0000x reference)
//
#include <hip/hip_runtime.h>

#define NCODE 512
#define NB    2048
#define NTHR  1024
#define FINF  __builtin_huge_valf()

// monotone f32 <-> u32 order-preserving map
__device__ __forceinline__ unsigned int fmap(float f) {
    unsigned int b = __float_as_uint(f);
    return b ^ ((b & 0x80000000u) ? 0xFFFFFFFFu : 0x80000000u);
}
__device__ __forceinline__ float funmap(unsigned int u) {
    unsigned int b = (u & 0x80000000u) ? (u ^ 0x80000000u) : ~u;
    return __uint_as_float(b);
}
__device__ __forceinline__ int bucket_of(float x, float vmin, float invw) {
    return (int)fminf(fmaxf((x - vmin) * invw, 0.0f), (float)(NB - 1));
}
// exact reference predicate: prefer upper code vh over lower vl at x in [vl,vh]
// (x-vl / vh-x match fabsf rounding there; tie -> smaller original index)
__device__ __forceinline__ bool pick_hi(float x, float vl, float vh,
                                        unsigned int il, unsigned int ih) {
    float dl = x - vl, dh = vh - x;
    return (dh < dl) || ((dh == dl) && (ih < il));
}

__global__ __launch_bounds__(NTHR) void quantize_fused(
        const float* __restrict__ emb,
        const float4* __restrict__ h4,
        float4* __restrict__ out4,
        int n4) {
    __shared__ float4 s_lut[NB];                  // 32 KB: self-contained buckets
    __shared__ unsigned int s_excl[NB + 1];       // code histogram -> starts
    __shared__ unsigned long long s_tmp[NCODE];   // bucket-grouped keys
    __shared__ float s_val[NCODE + 4];            // sorted codes (+build-read pad)
    __shared__ float s_thr[NCODE];                // 511 thresholds + FINF
    __shared__ unsigned short s_idx[NCODE];       // run-min original index
    __shared__ unsigned short s_j[NB + 1];        // per-bucket threshold base
    __shared__ float s_red[32];
    __shared__ unsigned int s_wt[16];

    const int t = threadIdx.x;
    const int lane = t & 63;
    const int wv = t >> 6;

    const int gid = blockIdx.x * NTHR + t;
    const bool live = (gid < n4);
    float4 x4 = make_float4(0.f, 0.f, 0.f, 0.f);
    if (live) x4 = h4[gid];                       // HBM latency hides under setup

    // ---- P0: zero histogram; load codes; wave min/max ----
    s_excl[t] = 0; s_excl[t + NTHR] = 0;
    if (t == 0) s_excl[NB] = 0;
    float v = 0.0f;
    if (t < NCODE) {                              // wave-uniform (waves 0..7)
        v = emb[t];
        float mn = v, mx = v;
        #pragma unroll
        for (int o = 32; o >= 1; o >>= 1) {
            mn = fminf(mn, __shfl_xor(mn, o));
            mx = fmaxf(mx, __shfl_xor(mx, o));
        }
        if (lane == 0) { s_red[wv] = mn; s_red[16 + wv] = mx; }
    }
    __syncthreads();                              // B1

    float vmin, invw;
    {
        float m0 = s_red[0], M0 = s_red[16];
        #pragma unroll
        for (int i = 1; i < 8; ++i) { m0 = fminf(m0, s_red[i]); M0 = fmaxf(M0, s_red[16 + i]); }
        vmin = m0;
        float range = M0 - m0;
        invw = (range > 0.0f) ? ((float)NB / range) : 0.0f;  // degenerate -> all bucket0 -> c3 fallback
    }

    // ---- P1: code histogram ----
    unsigned long long myk = 0; int b = 0; unsigned int slot = 0;
    if (t < NCODE) {
        myk = (((unsigned long long)fmap(v)) << 16) | (unsigned int)t;
        b = bucket_of(v, vmin, invw);
        slot = atomicAdd(&s_excl[b], 1u);
    }
    __syncthreads();                              // B2

    // ---- P2: exclusive scan over 2048 buckets (2/thread + wave shfl) ----
    {
        unsigned int h0 = s_excl[2 * t], h1 = s_excl[2 * t + 1];
        unsigned int ssum = h0 + h1, incl = ssum;
        #pragma unroll
        for (int o = 1; o < 64; o <<= 1) {
            unsigned int w = __shfl_up(incl, o);
            if (lane >= o) incl += w;
        }
        if (lane == 63) s_wt[wv] = incl;
        __syncthreads();                          // B3
        unsigned int base = 0;
        #pragma unroll
        for (int i = 0; i < 16; ++i) base += (i < wv) ? s_wt[i] : 0u;
        unsigned int c0 = base + incl - ssum;
        s_excl[2 * t] = c0; s_excl[2 * t + 1] = c0 + h0;
        if (t == NTHR - 1) s_excl[NB] = c0 + h0 + h1;
    }
    __syncthreads();                              // B4

    // ---- P3: scatter keys into bucket groups ----
    unsigned int lo_b = 0, hi_b = 0;
    if (t < NCODE) {
        lo_b = s_excl[b]; hi_b = s_excl[b + 1];
        s_tmp[lo_b + slot] = myk;
    }
    __syncthreads();                              // B5

    // ---- P4: within-bucket exact rank + run-min original index ----
    if (t < NCODE) {
        int r = 0; unsigned int minEq = (unsigned int)t;
        for (unsigned int j = lo_b; j < hi_b; ++j) {
            unsigned long long k2 = s_tmp[j];
            r += (k2 < myk) ? 1 : 0;
            float v2 = funmap((unsigned int)(k2 >> 16));
            if (v2 == v) {
                unsigned int i2 = (unsigned int)(k2 & 0xFFFFull);
                minEq = (i2 < minEq) ? i2 : minEq;
            }
        }
        int pos = (int)lo_b + r;
        s_val[pos] = v;
        s_idx[pos] = (unsigned short)minEq;
    } else if (t < NCODE + 4) {
        s_val[t] = 0.0f;                          // build-read pad
    }
    __syncthreads();                              // B6

    // ---- P5: exact decision thresholds between adjacent sorted codes ----
    if (t < NCODE - 1) {
        float vl = s_val[t], vh = s_val[t + 1];
        unsigned int il = s_idx[t], ih = s_idx[t + 1];
        float thrReg;
        if (vl == vh) {
            thrReg = vl;
        } else {
            unsigned int ulo = fmap(vl), uhi = fmap(vh);
            unsigned int um = fmap(0.5f * (vl + vh));
            unsigned int a  = (um - ulo >= 8u) ? um - 8u : ulo;
            unsigned int b2 = (uhi - um >= 8u) ? um + 8u : uhi;
            if (!pick_hi(funmap(a),  vl, vh, il, ih)) ulo = a;
            if ( pick_hi(funmap(b2), vl, vh, il, ih)) uhi = b2;
            while (uhi - ulo > 1u) {
                unsigned int mid = ulo + ((uhi - ulo) >> 1);
                if (pick_hi(funmap(mid), vl, vh, il, ih)) uhi = mid; else ulo = mid;
            }
            thrReg = funmap(uhi);                 // smallest f32 preferring vh
        }
        s_thr[t] = thrReg;
    } else if (t == NCODE - 1) {
        s_thr[t] = FINF;
    }
    __syncthreads();                              // B7

    // ---- P6: per-bucket threshold base via binary search (kills scan #2) ----
    {
        #pragma unroll
        for (int k = 0; k < 2; ++k) {
            int bb = t + k * NTHR;
            int r = 0;
            #pragma unroll
            for (int st = 256; st >= 1; st >>= 1) {
                float tv = s_thr[r + st - 1];
                r += (bucket_of(tv, vmin, invw) < bb) ? st : 0;
            }
            s_j[bb] = (unsigned short)r;
        }
        if (t == 0) s_j[NB] = (unsigned short)NCODE;
    }
    __syncthreads();                              // B8

    // ---- P7: self-contained LUT build ----
    {
        #pragma unroll
        for (int k = 0; k < 2; ++k) {
            int bb = t + k * NTHR;
            int j0 = s_j[bb], j1 = s_j[bb + 1];
            int cnt = j1 - j0;
            float4 L;
            if (cnt == 0) {
                L = make_float4(s_val[j0], 0.f, 0.f,
                                __uint_as_float((unsigned)j0));                 // c=0
            } else if (cnt == 1) {
                L = make_float4(s_val[j0], s_thr[j0], s_val[j0 + 1],
                                __uint_as_float((unsigned)j0 | (1u << 12)));    // c=1
            } else if (cnt == 2) {
                L = make_float4(s_thr[j0], s_thr[j0 + 1], 0.f,
                                __uint_as_float((unsigned)j0 | (2u << 12)));    // c=2
            } else {
                L = make_float4(0.f, 0.f, 0.f,
                                __uint_as_float(3u << 12));                     // c=3 rare
            }
            s_lut[bb] = L;
        }
    }
    __syncthreads();                              // B9

    // ---- P8: quantize — ~1 gather/elem common case ----
    if (live) {
        float xs[4] = {x4.x, x4.y, x4.z, x4.w};
        float rr[4];
        #pragma unroll
        for (int e = 0; e < 4; ++e) {
            float x = xs[e];
            float4 L = s_lut[bucket_of(x, vmin, invw)];
            unsigned int bits = __float_as_uint(L.w);
            unsigned int c = bits >> 12;
            float ans = (c == 1 && x >= L.y) ? L.z : L.x;
            if (c >= 2) {
                int r;
                if (c == 3) {                      // exact 9-step count (rare)
                    r = 0;
                    #pragma unroll
                    for (int st = 256; st >= 1; st >>= 1)
                        r += (s_thr[r + st - 1] <= x) ? st : 0;
                } else {
                    r = (int)(bits & 0xFFFu) + ((x >= L.x) ? 1 : 0) + ((x >= L.y) ? 1 : 0);
                }
                ans = s_val[r];
            }
            rr[e] = ans;
        }
        out4[gid] = make_float4(rr[0], rr[1], rr[2], rr[3]);
    }
}

extern "C" void kernel_launch(void* const* d_in, const int* in_sizes, int n_in,
                              void* d_out, int out_size, void* d_ws, size_t ws_size,
                              hipStream_t stream) {
    const float* h   = (const float*)d_in[0];
    const float* emb = (const float*)d_in[1];
    float* out = (float*)d_out;

    const int n = in_sizes[0];
    const int n4 = n / 4;                         // 262144
    const int blocks = (n4 + NTHR - 1) / NTHR;    // 256: one block per CU
    quantize_fused<<<blocks, NTHR, 0, stream>>>(
        emb, (const float4*)h, (float4*)out, n4);
}

// Round 6
// 13.111 us; speedup vs baseline: 1.0020x; 1.0020x over previous
//
#include <hip/hip_runtime.h>

#define NCODE 512
#define NB    2048
#define NTHR  1024
#define FINF  __builtin_huge_valf()

// monotone f32 <-> u32 order-preserving map
__device__ __forceinline__ unsigned int fmap(float f) {
    unsigned int b = __float_as_uint(f);
    return b ^ ((b & 0x80000000u) ? 0xFFFFFFFFu : 0x80000000u);
}
__device__ __forceinline__ float funmap(unsigned int u) {
    unsigned int b = (u & 0x80000000u) ? (u ^ 0x80000000u) : ~u;
    return __uint_as_float(b);
}
__device__ __forceinline__ int bucket_of(float x, float vmin, float invw) {
    return (int)fminf(fmaxf((x - vmin) * invw, 0.0f), (float)(NB - 1));
}
// exact reference predicate: prefer upper code vh over lower vl at x in [vl,vh]
// (x-vl / vh-x match fabsf rounding there; tie -> smaller original index)
__device__ __forceinline__ bool pick_hi(float x, float vl, float vh,
                                        unsigned int il, unsigned int ih) {
    float dl = x - vl, dh = vh - x;
    return (dh < dl) || ((dh == dl) && (ih < il));
}

__global__ __launch_bounds__(NTHR) void quantize_fused(
        const float* __restrict__ emb,
        const float4* __restrict__ h4,
        float4* __restrict__ out4,
        int n4) {
    __shared__ float4 s_lut[NB];                  // self-contained buckets
    __shared__ unsigned int s_excl[NB + 1];       // histogram -> exclusive starts
    __shared__ unsigned long long s_tmp[NCODE];   // bucket-grouped keys
    __shared__ float s_val[NCODE + 4];            // sorted codes (+build-read pad)
    __shared__ float s_thr[NCODE];                // 511 thresholds + FINF
    __shared__ unsigned short s_idx[NCODE];       // run-min original index
    __shared__ float s_red[32];
    __shared__ unsigned int s_wt[16];

    const int t = threadIdx.x;
    const int lane = t & 63;
    const int wv = t >> 6;

    const int gid = blockIdx.x * NTHR + t;
    const bool live = (gid < n4);
    float4 x4 = make_float4(0.f, 0.f, 0.f, 0.f);
    if (live) x4 = h4[gid];                       // HBM latency hides under setup

    // ---- P0: zero histogram; load codes; wave min/max ----
    s_excl[t] = 0; s_excl[t + NTHR] = 0;
    if (t == 0) s_excl[NB] = 0;
    float v = 0.0f;
    if (t < NCODE) {                              // wave-uniform (waves 0..7)
        v = emb[t];
        float mn = v, mx = v;
        #pragma unroll
        for (int o = 32; o >= 1; o >>= 1) {
            mn = fminf(mn, __shfl_xor(mn, o));
            mx = fmaxf(mx, __shfl_xor(mx, o));
        }
        if (lane == 0) { s_red[wv] = mn; s_red[16 + wv] = mx; }
    }
    __syncthreads();                              // B1

    float vmin, invw;
    {
        float m0 = s_red[0], M0 = s_red[16];
        #pragma unroll
        for (int i = 1; i < 8; ++i) { m0 = fminf(m0, s_red[i]); M0 = fmaxf(M0, s_red[16 + i]); }
        vmin = m0;
        float range = M0 - m0;
        invw = (range > 0.0f) ? ((float)NB / range) : 0.0f;  // degenerate -> all bucket0 -> c3 fallback
    }

    // ---- P1: code histogram ----
    unsigned long long myk = 0; int b = 0; unsigned int slot = 0;
    if (t < NCODE) {
        myk = (((unsigned long long)fmap(v)) << 16) | (unsigned int)t;
        b = bucket_of(v, vmin, invw);
        slot = atomicAdd(&s_excl[b], 1u);
    }
    __syncthreads();                              // B2

    // ---- P2: exclusive scan #1 over 2048 buckets (2/thread + wave shfl) ----
    {
        unsigned int h0 = s_excl[2 * t], h1 = s_excl[2 * t + 1];
        unsigned int ssum = h0 + h1, incl = ssum;
        #pragma unroll
        for (int o = 1; o < 64; o <<= 1) {
            unsigned int w = __shfl_up(incl, o);
            if (lane >= o) incl += w;
        }
        if (lane == 63) s_wt[wv] = incl;
        __syncthreads();                          // B3
        unsigned int base = 0;
        #pragma unroll
        for (int i = 0; i < 16; ++i) base += (i < wv) ? s_wt[i] : 0u;
        unsigned int c0 = base + incl - ssum;
        s_excl[2 * t] = c0; s_excl[2 * t + 1] = c0 + h0;
        if (t == NTHR - 1) s_excl[NB] = c0 + h0 + h1;
    }
    __syncthreads();                              // B4

    // ---- P3: scatter keys into bucket groups ----
    unsigned int lo_b = 0, hi_b = 0;
    if (t < NCODE) {
        lo_b = s_excl[b]; hi_b = s_excl[b + 1];
        s_tmp[lo_b + slot] = myk;
    }
    __syncthreads();                              // B5

    // ---- P4: within-bucket exact rank + run-min original index ----
    if (t < NCODE) {
        int r = 0; unsigned int minEq = (unsigned int)t;
        for (unsigned int j = lo_b; j < hi_b; ++j) {
            unsigned long long k2 = s_tmp[j];
            r += (k2 < myk) ? 1 : 0;
            float v2 = funmap((unsigned int)(k2 >> 16));
            if (v2 == v) {
                unsigned int i2 = (unsigned int)(k2 & 0xFFFFull);
                minEq = (i2 < minEq) ? i2 : minEq;
            }
        }
        int pos = (int)lo_b + r;
        s_val[pos] = v;
        s_idx[pos] = (unsigned short)minEq;
    } else if (t < NCODE + 4) {
        s_val[t] = 0.0f;                          // build-read pad
    }
    __syncthreads();                              // B6

    // ---- P5: thresholds (t<511) in parallel with excl re-zero (t>=512) ----
    float thrReg = FINF;
    if (t < NCODE - 1) {
        float vl = s_val[t], vh = s_val[t + 1];
        unsigned int il = s_idx[t], ih = s_idx[t + 1];
        if (vl == vh) {
            thrReg = vl;
        } else {
            unsigned int ulo = fmap(vl), uhi = fmap(vh);
            unsigned int um = fmap(0.5f * (vl + vh));
            unsigned int a  = (um - ulo >= 8u) ? um - 8u : ulo;
            unsigned int b2 = (uhi - um >= 8u) ? um + 8u : uhi;
            if (!pick_hi(funmap(a),  vl, vh, il, ih)) ulo = a;
            if ( pick_hi(funmap(b2), vl, vh, il, ih)) uhi = b2;
            while (uhi - ulo > 1u) {
                unsigned int mid = ulo + ((uhi - ulo) >> 1);
                if (pick_hi(funmap(mid), vl, vh, il, ih)) uhi = mid; else ulo = mid;
            }
            thrReg = funmap(uhi);                 // smallest f32 preferring vh
        }
        s_thr[t] = thrReg;
    } else if (t == NCODE - 1) {
        s_thr[t] = FINF;
    } else {
        int t2 = t - NCODE;                       // 512 threads re-zero 2049 entries
        s_excl[t2] = 0; s_excl[t2 + 512] = 0; s_excl[t2 + 1024] = 0; s_excl[t2 + 1536] = 0;
        if (t2 == 0) s_excl[NB] = 0;
    }
    __syncthreads();                              // B7

    // ---- P6: threshold histogram ----
    if (t < NCODE - 1) atomicAdd(&s_excl[bucket_of(thrReg, vmin, invw)], 1u);
    __syncthreads();                              // B8

    // ---- P7: exclusive scan #2 (identical structure) ----
    {
        unsigned int h0 = s_excl[2 * t], h1 = s_excl[2 * t + 1];
        unsigned int ssum = h0 + h1, incl = ssum;
        #pragma unroll
        for (int o = 1; o < 64; o <<= 1) {
            unsigned int w = __shfl_up(incl, o);
            if (lane >= o) incl += w;
        }
        if (lane == 63) s_wt[wv] = incl;
        __syncthreads();                          // B9
        unsigned int base = 0;
        #pragma unroll
        for (int i = 0; i < 16; ++i) base += (i < wv) ? s_wt[i] : 0u;
        unsigned int c0 = base + incl - ssum;
        s_excl[2 * t] = c0; s_excl[2 * t + 1] = c0 + h0;
        if (t == NTHR - 1) s_excl[NB] = c0 + h0 + h1;
    }
    __syncthreads();                              // B10

    // ---- P8: self-contained LUT build (2 buckets/thread) ----
    {
        #pragma unroll
        for (int k = 0; k < 2; ++k) {
            int bb = 2 * t + k;
            unsigned int j0 = s_excl[bb];
            unsigned int cnt = s_excl[bb + 1] - j0;
            float4 L;
            if (cnt == 0u) {
                L = make_float4(s_val[j0], 0.f, 0.f,
                                __uint_as_float(j0));                        // c=0: answer in L.x
            } else if (cnt == 1u) {
                L = make_float4(s_val[j0], s_thr[j0], s_val[j0 + 1],
                                __uint_as_float(j0 | (1u << 12)));           // c=1: v0,thr,v1
            } else if (cnt == 2u) {
                L = make_float4(s_thr[j0], s_thr[j0 + 1], 0.f,
                                __uint_as_float(j0 | (2u << 12)));           // c=2: 2 thr + base
            } else {
                L = make_float4(0.f, 0.f, 0.f,
                                __uint_as_float(3u << 12));                  // c=3: exact fallback
            }
            s_lut[bb] = L;
        }
    }
    __syncthreads();                              // B11

    // ---- P9: quantize — ~1 gather/elem common case ----
    if (live) {
        float xs[4] = {x4.x, x4.y, x4.z, x4.w};
        float rr[4];
        #pragma unroll
        for (int e = 0; e < 4; ++e) {
            float x = xs[e];
            float4 L = s_lut[bucket_of(x, vmin, invw)];
            unsigned int bits = __float_as_uint(L.w);
            unsigned int c = bits >> 12;
            float ans = (c == 1 && x >= L.y) ? L.z : L.x;
            if (c >= 2) {
                int r;
                if (c == 3) {                     // rare: exact 9-step count
                    r = 0;
                    #pragma unroll
                    for (int st = 256; st >= 1; st >>= 1)
                        r += (s_thr[r + st - 1] <= x) ? st : 0;
                } else {
                    r = (int)(bits & 0xFFFu) + ((x >= L.x) ? 1 : 0) + ((x >= L.y) ? 1 : 0);
                }
                ans = s_val[r];
            }
            rr[e] = ans;
        }
        out4[gid] = make_float4(rr[0], rr[1], rr[2], rr[3]);
    }
}

extern "C" void kernel_launch(void* const* d_in, const int* in_sizes, int n_in,
                              void* d_out, int out_size, void* d_ws, size_t ws_size,
                              hipStream_t stream) {
    const float* h   = (const float*)d_in[0];
    const float* emb = (const float*)d_in[1];
    float* out = (float*)d_out;

    const int n = in_sizes[0];
    const int n4 = n / 4;                         // 262144
    const int blocks = (n4 + NTHR - 1) / NTHR;    // 256: one block per CU
    quantize_fused<<<blocks, NTHR, 0, stream>>>(
        emb, (const float4*)h, (float4*)out, n4);
}

// Round 7
// 11.696 us; speedup vs baseline: 1.1232x; 1.1210x over previous
//
#include <hip/hip_runtime.h>

#define NCODE 512
#define NB    2048
#define NTHR  1024
#define FINF  __builtin_huge_valf()

// monotone f32 <-> u32 order-preserving map
__device__ __forceinline__ unsigned int fmap(float f) {
    unsigned int b = __float_as_uint(f);
    return b ^ ((b & 0x80000000u) ? 0xFFFFFFFFu : 0x80000000u);
}
__device__ __forceinline__ float funmap(unsigned int u) {
    unsigned int b = (u & 0x80000000u) ? (u ^ 0x80000000u) : ~u;
    return __uint_as_float(b);
}
__device__ __forceinline__ int bucket_of(float x, float vmin, float invw) {
    float bf = fminf(fmaxf((x - vmin) * invw, 0.0f), (float)(NB - 1));
    return (int)bf;
}
// exact reference predicate: prefer upper code vh over lower vl at point x
// (x in [vl,vh]; dl,dh match jnp.abs f32 rounding; tie -> smaller orig index)
__device__ __forceinline__ bool pick_hi(float x, float vl, float vh,
                                        unsigned int il, unsigned int ih) {
    float dl = x - vl;
    float dh = vh - x;
    return (dh < dl) || ((dh == dl) && (ih < il));
}

__global__ __launch_bounds__(NTHR) void quantize_fused(
        const float* __restrict__ emb,
        const float4* __restrict__ h4,
        float4* __restrict__ out4,
        int n4) {
    __shared__ float4 s_lut[NB];                 // (thrA,thrB,thrC, bits=j|flag)
    __shared__ unsigned int s_excl[NB + 1];
    __shared__ unsigned long long s_tmp[NCODE];
    __shared__ float s_val[NCODE + 16];          // sorted codes (+pad)
    __shared__ float s_thr[NCODE];               // 511 sorted thresholds + INF
    __shared__ unsigned short s_idx[NCODE];      // run-min original index
    __shared__ float s_red[32];
    __shared__ unsigned int s_wt[16];

    const int t = threadIdx.x;
    const int lane = t & 63;
    const int wv = t >> 6;

    const int gid = blockIdx.x * NTHR + t;
    const bool live = (gid < n4);
    float4 x4 = make_float4(0.f, 0.f, 0.f, 0.f);
    if (live) x4 = h4[gid];                      // prefetch: latency hides under setup

    s_excl[t] = 0; s_excl[t + NTHR] = 0;
    if (t == 0) s_excl[NB] = 0;

    float v = 0.0f;
    if (t < NCODE) {
        v = emb[t];
        float mn = v, mx = v;
        #pragma unroll
        for (int o = 32; o >= 1; o >>= 1) {
            mn = fminf(mn, __shfl_xor(mn, o));
            mx = fmaxf(mx, __shfl_xor(mx, o));
        }
        if (lane == 0) { s_red[wv] = mn; s_red[16 + wv] = mx; }
    }
    __syncthreads();                                   // B1

    float vmin, invw;
    {
        float m0 = s_red[0], M0 = s_red[16];
        #pragma unroll
        for (int i = 1; i < 8; ++i) { m0 = fminf(m0, s_red[i]); M0 = fmaxf(M0, s_red[16 + i]); }
        vmin = m0;
        float range = M0 - m0;
        invw = (range > 0.0f) ? ((float)NB / range) : 0.0f;  // degenerate -> all bucket0 -> flagged -> exact fallback
    }

    // ---- code histogram ----
    int b = 0; unsigned int slot = 0;
    unsigned long long myk = 0;
    if (t < NCODE) {
        myk = (((unsigned long long)fmap(v)) << 16) | (unsigned int)t;
        b = bucket_of(v, vmin, invw);
        slot = atomicAdd(&s_excl[b], 1u);
    }
    __syncthreads();                                   // B2

    // ---- scan #1 over 2048 buckets (2/thread + wave shfl scan) ----
    {
        unsigned int h0 = s_excl[2 * t], h1 = s_excl[2 * t + 1];
        unsigned int s = h0 + h1, incl = s;
        #pragma unroll
        for (int o = 1; o < 64; o <<= 1) {
            unsigned int w = __shfl_up(incl, o);
            if (lane >= o) incl += w;
        }
        if (lane == 63) s_wt[wv] = incl;
        __syncthreads();                               // B3
        unsigned int base = 0;
        #pragma unroll
        for (int i = 0; i < 16; ++i) base += (i < wv) ? s_wt[i] : 0u;
        unsigned int c0 = base + incl - s;
        s_excl[2 * t] = c0; s_excl[2 * t + 1] = c0 + h0;
        if (t == NTHR - 1) s_excl[NB] = c0 + h0 + h1;
    }
    __syncthreads();                                   // B4

    // ---- scatter keys into bucket groups ----
    unsigned int lo_b = 0, hi_b = 0;
    if (t < NCODE) {
        lo_b = s_excl[b]; hi_b = s_excl[b + 1];
        s_tmp[lo_b + slot] = myk;
    }
    __syncthreads();                                   // B5

    // ---- exact within-bucket rank + run-min original index ----
    if (t < NCODE) {
        int r = 0; unsigned int minEq = (unsigned int)t;
        for (unsigned int j = lo_b; j < hi_b; ++j) {
            unsigned long long k2 = s_tmp[j];
            r += (k2 < myk) ? 1 : 0;
            float v2 = funmap((unsigned int)(k2 >> 16));
            if (v2 == v) {
                unsigned int i2 = (unsigned int)(k2 & 0xFFFFull);
                minEq = (i2 < minEq) ? i2 : minEq;
            }
        }
        int pos = (int)lo_b + r;
        s_val[pos] = v;
        s_idx[pos] = (unsigned short)minEq;
    } else if (t < NCODE + 16) {
        s_val[t] = FINF;
    }
    __syncthreads();                                   // B6

    // ---- thresholds (t<511) in parallel with excl re-zero (t>=512) ----
    float thrReg = FINF;
    if (t < NCODE - 1) {
        float vl = s_val[t], vh = s_val[t + 1];
        unsigned int il = s_idx[t], ih = s_idx[t + 1];
        if (vl == vh) {
            thrReg = vl;                                // same value: any consistent thr
        } else {
            unsigned int ulo = fmap(vl), uhi = fmap(vh);
            unsigned int um = fmap(0.5f * (vl + vh));   // in [ulo,uhi] by rounding monotonicity
            unsigned int a  = (um - ulo >= 8u) ? um - 8u : ulo;
            unsigned int b2 = (uhi - um >= 8u) ? um + 8u : uhi;
            if (!pick_hi(funmap(a),  vl, vh, il, ih)) ulo = a;   // tighten window if valid
            if ( pick_hi(funmap(b2), vl, vh, il, ih)) uhi = b2;
            while (uhi - ulo > 1u) {                    // <=4 iters windowed, <=32 worst
                unsigned int mid = ulo + ((uhi - ulo) >> 1);
                if (pick_hi(funmap(mid), vl, vh, il, ih)) uhi = mid; else ulo = mid;
            }
            thrReg = funmap(uhi);                       // smallest f32 x preferring vh
        }
        s_thr[t] = thrReg;
    } else if (t == NCODE - 1) {
        s_thr[t] = FINF;
    } else {
        int t2 = t - NCODE;                             // 512 threads re-zero 2049 entries
        s_excl[t2] = 0; s_excl[t2 + 512] = 0; s_excl[t2 + 1024] = 0; s_excl[t2 + 1536] = 0;
        if (t2 == 0) s_excl[NB] = 0;
    }
    __syncthreads();                                   // B7

    // ---- threshold histogram ----
    if (t < NCODE - 1) atomicAdd(&s_excl[bucket_of(thrReg, vmin, invw)], 1u);
    __syncthreads();                                   // B8

    // ---- scan #2 (identical) ----
    {
        unsigned int h0 = s_excl[2 * t], h1 = s_excl[2 * t + 1];
        unsigned int s = h0 + h1, incl = s;
        #pragma unroll
        for (int o = 1; o < 64; o <<= 1) {
            unsigned int w = __shfl_up(incl, o);
            if (lane >= o) incl += w;
        }
        if (lane == 63) s_wt[wv] = incl;
        __syncthreads();                               // B9
        unsigned int base = 0;
        #pragma unroll
        for (int i = 0; i < 16; ++i) base += (i < wv) ? s_wt[i] : 0u;
        unsigned int c0 = base + incl - s;
        s_excl[2 * t] = c0; s_excl[2 * t + 1] = c0 + h0;
        if (t == NTHR - 1) s_excl[NB] = c0 + h0 + h1;
    }
    __syncthreads();                                   // B10

    // ---- build LUT: up to 3 thresholds + base index per bucket, one float4 ----
    #pragma unroll
    for (int k = 0; k < 2; ++k) {
        int bb = 2 * t + k;
        unsigned int j = s_excl[bb];
        unsigned int cnt = s_excl[bb + 1] - j;
        float4 w;
        if (cnt <= 3u) {
            w.x = (cnt >= 1u) ? s_thr[j]     : FINF;
            w.y = (cnt >= 2u) ? s_thr[j + 1] : FINF;
            w.z = (cnt >= 3u) ? s_thr[j + 2] : FINF;
            w.w = __uint_as_float(j);
        } else {
            w.x = FINF; w.y = FINF; w.z = FINF;
            w.w = __uint_as_float(j | 0x80000000u);     // rare: exact full search
        }
        s_lut[bb] = w;
    }
    __syncthreads();                                   // B11

    // ---- quantize: 1 b128 + 3 cmps (+1 b32) per element ----
    if (live) {
        float xs[4] = {x4.x, x4.y, x4.z, x4.w};
        float rr[4];
        #pragma unroll
        for (int e = 0; e < 4; ++e) {
            float x = xs[e];
            float4 L = s_lut[bucket_of(x, vmin, invw)];
            unsigned int bits = __float_as_uint(L.w);
            int r = (int)(bits & 0xFFFFu);
            r += (x >= L.x) ? 1 : 0;
            r += (x >= L.y) ? 1 : 0;
            r += (x >= L.z) ? 1 : 0;
            if (bits & 0x80000000u) {                  // flagged bucket: exact count
                r = 0;
                #pragma unroll
                for (int st = 256; st >= 1; st >>= 1)
                    r += (s_thr[r + st - 1] <= x) ? st : 0;
            }
            rr[e] = s_val[r];
        }
        out4[gid] = make_float4(rr[0], rr[1], rr[2], rr[3]);
    }
}

extern "C" void kernel_launch(void* const* d_in, const int* in_sizes, int n_in,
                              void* d_out, int out_size, void* d_ws, size_t ws_size,
                              hipStream_t stream) {
    const float* h   = (const float*)d_in[0];
    const float* emb = (const float*)d_in[1];
    float* out = (float*)d_out;

    const int n = in_sizes[0];
    const int n4 = n / 4;                        // 262144
    const int blocks = (n4 + NTHR - 1) / NTHR;   // 256: one block per CU
    quantize_fused<<<blocks, NTHR, 0, stream>>>(
        emb, (const float4*)h, (float4*)out, n4);
}